// Round 12
// baseline (69.436 us; speedup 1.0000x reference)
//
#include <hip/hip_runtime.h>
#include <hip/hip_fp16.h>

// HalutMatmul forward on MI355X.
// Per row n: h[c][p] = sum_d I[n, c*9+d] * A[c][d][p]   (c=0..15, p=0..3)
//            code_c  = 4-level tree descent: bit_l = (h[c][l] > T[c*15 + node_l])
//            out[n][m] = sum_c L[m][c][code_c]
//
// Round-12: occupancy attack with a clean ledger. R10 (LDS cut) and R11 (VALU
// cut) both barely moved -> no pipe is throughput-bound; the kernel is
// stall-bound at 8 waves/CU (grid was 2 blocks/CU every round). Changes:
//  - 128-row blocks, grid=1024, LDS=34KB -> 4 blocks/CU = 16 waves/CU.
//  - no I staging: hash lanes read global directly (L1 absorbs the 36B-stride).
//  - codes packed in-wave via 2x shfl_xor -> 2KB sCodes, no hash/gather barrier.
//  - gather bank-exact: phys uint2 idx = i*512 + col*2 + mh -> (p*2+mh)%16
//    bank-pairs, exactly 2-way (free). R11 f32-guard hash (codes bit-exact).

#define NROWS (1024 * 128)

typedef __attribute__((ext_vector_type(2))) float f32x2;

__global__ __launch_bounds__(256, 4) void halut_fwd(
    const float* __restrict__ I,
    const float* __restrict__ A,
    const float* __restrict__ T,
    const float* __restrict__ L,
    float* __restrict__ out)
{
    __shared__ uint32_t sLut[8192];   // 32KB f16 LUT; reused as epilogue staging
    __shared__ uint32_t sCodes[512];  // 128 rows x 4 u32 (16 codes, 8b each)

    const int tid  = threadIdx.x;
    const int w    = tid >> 6;
    const int lane = tid & 63;
    const int cB   = lane & 15;       // hash: codebook
    const int g    = lane >> 4;       // hash: row-in-pass

    // ---- per-lane constants: codebook cB's A and T in VGPRs ----
    f32x2 a01[9], a23[9];
    {
        const float4* ap4 = (const float4*)(A + cB * 36);   // 144B-aligned
        #pragma unroll
        for (int i = 0; i < 9; ++i) {
            const float4 v = ap4[i];
            a01[i] = (f32x2){v.x, v.y};
            a23[i] = (f32x2){v.z, v.w};
        }
    }
    float Tf[15];
    #pragma unroll
    for (int j = 0; j < 15; ++j) Tf[j] = T[cB * 15 + j];

    // ---- stage f16 LUT: phys uint2 idx = i*512 + col*2 + mh (col = tid) ----
    // b128 write combines (mh=0 -> m=4i+{0..3}, mh=1 -> m=32+4i+{0..3})
    {
        uint4* dst = (uint4*)sLut;                 // uint4 idx = i*256 + tid
        #pragma unroll
        for (int i = 0; i < 8; ++i) {
            uint32_t wv[4];
            #pragma unroll
            for (int mh2 = 0; mh2 < 2; ++mh2) {
                const int mb = mh2 * 32 + 4 * i;
                const float fa = L[(mb + 0) * 256 + tid];
                const float fb = L[(mb + 1) * 256 + tid];
                const float fc = L[(mb + 2) * 256 + tid];
                const float fd = L[(mb + 3) * 256 + tid];
                wv[mh2*2+0] = ((uint32_t)__half_as_ushort(__float2half_rn(fb)) << 16)
                            |  (uint32_t)__half_as_ushort(__float2half_rn(fa));
                wv[mh2*2+1] = ((uint32_t)__half_as_ushort(__float2half_rn(fd)) << 16)
                            |  (uint32_t)__half_as_ushort(__float2half_rn(fc));
            }
            dst[i * 256 + tid] = make_uint4(wv[0], wv[1], wv[2], wv[3]);
        }
    }
    __syncthreads();

    // ---- hash: 8 passes x 4 rows, direct global reads, 1-deep prefetch ----
    const int brow0 = blockIdx.x * 128;
    const float* gb = I + (size_t)(brow0 + w * 32 + g) * 144 + cB * 9;

    float xb[2][9];
    #pragma unroll
    for (int d = 0; d < 9; ++d) xb[0][d] = gb[d];

    #pragma unroll
    for (int ps = 0; ps < 8; ++ps) {                 // fully unrolled: static idx
        const float* xc = xb[ps & 1];
        if (ps < 7) {
            float* xn = xb[(ps + 1) & 1];
            #pragma unroll
            for (int d = 0; d < 9; ++d) xn[d] = gb[(ps + 1) * 576 + d];
        }
        f32x2 h01 = (f32x2){0.f, 0.f}, h23 = (f32x2){0.f, 0.f};
        #pragma unroll
        for (int d = 0; d < 9; ++d) {
            const f32x2 xx = (f32x2){xc[d], xc[d]};
            h01 = __builtin_elementwise_fma(xx, a01[d], h01);
            h23 = __builtin_elementwise_fma(xx, a23[d], h23);
        }
        const float hh[4] = {h01.x, h01.y, h23.x, h23.y};
        uint32_t mk = 0, bl = 0;
        #pragma unroll
        for (int j = 0; j < 15; ++j) {
            const int lv = (j == 0) ? 0 : (j < 3) ? 1 : (j < 7) ? 2 : 3;
            const float b = hh[lv] - Tf[j];
            mk |= (b > 0.f) ? (1u << j) : 0u;
            bl |= (fabsf(b) < 1e-3f) ? 1u : 0u;
        }
        if (bl) {   // rare borderline: exact f64, FMA order of rounds 1-10
            double h0 = 0.0, h1 = 0.0, h2 = 0.0, h3 = 0.0;
            #pragma unroll
            for (int d = 0; d < 9; ++d) {
                const double x = (double)xc[d];
                h0 = fma(x, (double)a01[d].x, h0);
                h1 = fma(x, (double)a01[d].y, h1);
                h2 = fma(x, (double)a23[d].x, h2);
                h3 = fma(x, (double)a23[d].y, h3);
            }
            const double hd[4] = {h0, h1, h2, h3};
            mk = 0;
            #pragma unroll
            for (int j = 0; j < 15; ++j) {
                const int lv = (j == 0) ? 0 : (j < 3) ? 1 : (j < 7) ? 2 : 3;
                mk |= (hd[lv] > (double)Tf[j]) ? (1u << j) : 0u;
            }
        }
        int p =       (int)(mk & 1u);
        p = 2 * p + (int)((mk >> (1 + p)) & 1u);
        p = 2 * p + (int)((mk >> (3 + p)) & 1u);
        p = 2 * p + (int)((mk >> (7 + p)) & 1u);

        // pack 4 codes/u32 across the cB-quad; one lane per quad writes
        uint32_t v = (uint32_t)p << (8 * (cB & 3));
        v |= __shfl_xor(v, 1);
        v |= __shfl_xor(v, 2);
        if ((lane & 3) == 0)
            sCodes[(w * 32 + ps * 4 + g) * 4 + (cB >> 2)] = v;
    }

    // ---- gather: 2 thr/row, bank-exact 2-way-free b64 reads ----
    const int lr = tid >> 1;          // 0..127
    const int mh = tid & 1;           // m-half
    const uint4 cw = ((const uint4*)sCodes)[lr];   // same-wave rows: no barrier

    __half2 acc2[16];
    #pragma unroll
    for (int k = 0; k < 16; ++k) acc2[k] = __floats2half2_rn(0.f, 0.f);

    const uint2* lut2 = (const uint2*)sLut;
    #pragma unroll 4
    for (int c = 0; c < 16; ++c) {
        const uint32_t cdw = (c < 4) ? cw.x : (c < 8) ? cw.y : (c < 12) ? cw.z : cw.w;
        const int p    = (int)((cdw >> ((c & 3) * 8)) & 15u);
        const int col2 = (c * 16 + p) * 2 + mh;
        #pragma unroll
        for (int i = 0; i < 8; ++i) {             // m-quad = mh*8+i
            const uint2 uv = lut2[i * 512 + col2];
            acc2[2*i]   = __hadd2(acc2[2*i],   *(const __half2*)&uv.x);
            acc2[2*i+1] = __hadd2(acc2[2*i+1], *(const __half2*)&uv.y);
        }
    }

    // ---- epilogue: swizzled LDS transpose (proven), 128 rows, one pass ----
    __syncthreads();                  // all gathers done; LUT region dead
    float* sO = (float*)sLut;         // [128 rows][64 m], 16B-chunk swizzle
    #pragma unroll
    for (int k2 = 0; k2 < 8; ++k2) {
        const int ch = mh * 8 + k2;   // global float4 chunk = m/4
        const float4 v = make_float4(__low2float (acc2[2*k2]),
                                     __high2float(acc2[2*k2]),
                                     __low2float (acc2[2*k2+1]),
                                     __high2float(acc2[2*k2+1]));
        *(float4*)&sO[(lr << 6) + ((ch ^ (lr & 15)) << 2)] = v;
    }
    __syncthreads();

    float4* op = (float4*)(out + (size_t)blockIdx.x * (128 * 64));
    #pragma unroll
    for (int j = 0; j < 8; ++j) {     // 2048 float4 = 32 KiB, contiguous
        const int F  = tid + (j << 8);
        const int r2 = F >> 4;
        const int m2 = F & 15;
        op[F] = *(const float4*)&sO[(r2 << 6) + ((m2 ^ (r2 & 15)) << 2)];
    }
}

extern "C" void kernel_launch(void* const* d_in, const int* in_sizes, int n_in,
                              void* d_out, int out_size, void* d_ws, size_t ws_size,
                              hipStream_t stream) {
    const float* I = (const float*)d_in[0];
    const float* A = (const float*)d_in[1];
    const float* T = (const float*)d_in[2];
    const float* L = (const float*)d_in[3];
    float* outp = (float*)d_out;

    const int nblocks = NROWS / 128;   // 1024 blocks x 256 threads
    halut_fwd<<<nblocks, 256, 0, stream>>>(I, A, T, L, outp);
}

// Round 13
// 53.410 us; speedup vs baseline: 1.3000x; 1.3000x over previous
//
#include <hip/hip_runtime.h>
#include <hip/hip_fp16.h>

// HalutMatmul forward on MI355X.
// Per row n: h[c][p] = sum_d I[n, c*9+d] * A[c][d][p]   (c=0..15, p=0..3)
//            code_c  = 4-level tree descent: bit_l = (h[c][l] > T[c*15 + node_l])
//            out[n][m] = sum_c L[m][c][code_c]
//
// Round-13: clean occupancy experiment. R12's structure was right but
// __launch_bounds__(256,4) forced VGPR=64 against ~110 demand -> scratch
// spills (WRITE 108MB, 69us). Same kernel with (256,3): VGPR cap 168, no
// spills, LDS 34KB -> 3 blocks/CU = 12 waves/CU (vs 8 in all sub-30us
// rounds). Isolated A/B: R10 (8 waves, 27.4us) vs this (12 waves).
//  - no I staging: hash lanes read global directly (L1 absorbs 36B stride).
//  - codes packed in-wave via shfl_xor -> 2KB sCodes.
//  - f32 hash + 1e-3 borderline guard + exact-f64 fallback (codes bit-exact
//    with rounds 1-10; absmax 0.0039 proven in R11/R12).

#define NROWS (1024 * 128)

typedef __attribute__((ext_vector_type(2))) float f32x2;

__global__ __launch_bounds__(256, 3) void halut_fwd(
    const float* __restrict__ I,
    const float* __restrict__ A,
    const float* __restrict__ T,
    const float* __restrict__ L,
    float* __restrict__ out)
{
    __shared__ uint32_t sLut[8192];   // 32KB f16 LUT; reused as epilogue staging
    __shared__ uint32_t sCodes[512];  // 128 rows x 4 u32 (16 codes, 8b each)

    const int tid  = threadIdx.x;
    const int w    = tid >> 6;
    const int lane = tid & 63;
    const int cB   = lane & 15;       // hash: codebook
    const int g    = lane >> 4;       // hash: row-in-pass

    // ---- per-lane constants: codebook cB's A and T in VGPRs ----
    f32x2 a01[9], a23[9];
    {
        const float4* ap4 = (const float4*)(A + cB * 36);   // 144B-aligned
        #pragma unroll
        for (int i = 0; i < 9; ++i) {
            const float4 v = ap4[i];
            a01[i] = (f32x2){v.x, v.y};
            a23[i] = (f32x2){v.z, v.w};
        }
    }
    float Tf[15];
    #pragma unroll
    for (int j = 0; j < 15; ++j) Tf[j] = T[cB * 15 + j];

    // ---- stage f16 LUT: phys uint2 idx = i*512 + col*2 + mh (col = tid) ----
    {
        uint4* dst = (uint4*)sLut;                 // uint4 idx = i*256 + tid
        #pragma unroll
        for (int i = 0; i < 8; ++i) {
            uint32_t wv[4];
            #pragma unroll
            for (int mh2 = 0; mh2 < 2; ++mh2) {
                const int mb = mh2 * 32 + 4 * i;
                const float fa = L[(mb + 0) * 256 + tid];
                const float fb = L[(mb + 1) * 256 + tid];
                const float fc = L[(mb + 2) * 256 + tid];
                const float fd = L[(mb + 3) * 256 + tid];
                wv[mh2*2+0] = ((uint32_t)__half_as_ushort(__float2half_rn(fb)) << 16)
                            |  (uint32_t)__half_as_ushort(__float2half_rn(fa));
                wv[mh2*2+1] = ((uint32_t)__half_as_ushort(__float2half_rn(fd)) << 16)
                            |  (uint32_t)__half_as_ushort(__float2half_rn(fc));
            }
            dst[i * 256 + tid] = make_uint4(wv[0], wv[1], wv[2], wv[3]);
        }
    }
    __syncthreads();

    // ---- hash: 8 passes x 4 rows, direct global reads, 1-deep prefetch ----
    const int brow0 = blockIdx.x * 128;
    const float* gb = I + (size_t)(brow0 + w * 32 + g) * 144 + cB * 9;

    float xb[2][9];
    #pragma unroll
    for (int d = 0; d < 9; ++d) xb[0][d] = gb[d];

    #pragma unroll
    for (int ps = 0; ps < 8; ++ps) {                 // fully unrolled: static idx
        const float* xc = xb[ps & 1];
        if (ps < 7) {
            float* xn = xb[(ps + 1) & 1];
            #pragma unroll
            for (int d = 0; d < 9; ++d) xn[d] = gb[(ps + 1) * 576 + d];
        }
        f32x2 h01 = (f32x2){0.f, 0.f}, h23 = (f32x2){0.f, 0.f};
        #pragma unroll
        for (int d = 0; d < 9; ++d) {
            const f32x2 xx = (f32x2){xc[d], xc[d]};
            h01 = __builtin_elementwise_fma(xx, a01[d], h01);
            h23 = __builtin_elementwise_fma(xx, a23[d], h23);
        }
        const float hh[4] = {h01.x, h01.y, h23.x, h23.y};
        uint32_t mk = 0, bl = 0;
        #pragma unroll
        for (int j = 0; j < 15; ++j) {
            const int lv = (j == 0) ? 0 : (j < 3) ? 1 : (j < 7) ? 2 : 3;
            const float b = hh[lv] - Tf[j];
            mk |= (b > 0.f) ? (1u << j) : 0u;
            bl |= (fabsf(b) < 1e-3f) ? 1u : 0u;
        }
        if (bl) {   // rare borderline: exact f64, FMA order of rounds 1-10
            double h0 = 0.0, h1 = 0.0, h2 = 0.0, h3 = 0.0;
            #pragma unroll
            for (int d = 0; d < 9; ++d) {
                const double x = (double)xc[d];
                h0 = fma(x, (double)a01[d].x, h0);
                h1 = fma(x, (double)a01[d].y, h1);
                h2 = fma(x, (double)a23[d].x, h2);
                h3 = fma(x, (double)a23[d].y, h3);
            }
            const double hd[4] = {h0, h1, h2, h3};
            mk = 0;
            #pragma unroll
            for (int j = 0; j < 15; ++j) {
                const int lv = (j == 0) ? 0 : (j < 3) ? 1 : (j < 7) ? 2 : 3;
                mk |= (hd[lv] > (double)Tf[j]) ? (1u << j) : 0u;
            }
        }
        int p =       (int)(mk & 1u);
        p = 2 * p + (int)((mk >> (1 + p)) & 1u);
        p = 2 * p + (int)((mk >> (3 + p)) & 1u);
        p = 2 * p + (int)((mk >> (7 + p)) & 1u);

        // pack 4 codes/u32 across the cB-quad; one lane per quad writes
        uint32_t v = (uint32_t)p << (8 * (cB & 3));
        v |= __shfl_xor(v, 1);
        v |= __shfl_xor(v, 2);
        if ((lane & 3) == 0)
            sCodes[(w * 32 + ps * 4 + g) * 4 + (cB >> 2)] = v;
    }

    // ---- gather: 2 thr/row, avg-2-way b64 reads ----
    const int lr = tid >> 1;          // 0..127
    const int mh = tid & 1;           // m-half
    const uint4 cw = ((const uint4*)sCodes)[lr];   // same-wave rows: no barrier

    __half2 acc2[16];
    #pragma unroll
    for (int k = 0; k < 16; ++k) acc2[k] = __floats2half2_rn(0.f, 0.f);

    const uint2* lut2 = (const uint2*)sLut;
    #pragma unroll 4
    for (int c = 0; c < 16; ++c) {
        const uint32_t cdw = (c < 4) ? cw.x : (c < 8) ? cw.y : (c < 12) ? cw.z : cw.w;
        const int p    = (int)((cdw >> ((c & 3) * 8)) & 15u);
        const int col2 = (c * 16 + p) * 2 + mh;
        #pragma unroll
        for (int i = 0; i < 8; ++i) {             // m-quad = mh*8+i
            const uint2 uv = lut2[i * 512 + col2];
            acc2[2*i]   = __hadd2(acc2[2*i],   *(const __half2*)&uv.x);
            acc2[2*i+1] = __hadd2(acc2[2*i+1], *(const __half2*)&uv.y);
        }
    }

    // ---- epilogue: swizzled LDS transpose (proven), 128 rows, one pass ----
    __syncthreads();                  // all gathers done; LUT region dead
    float* sO = (float*)sLut;         // [128 rows][64 m], 16B-chunk swizzle
    #pragma unroll
    for (int k2 = 0; k2 < 8; ++k2) {
        const int ch = mh * 8 + k2;   // global float4 chunk = m/4
        const float4 v = make_float4(__low2float (acc2[2*k2]),
                                     __high2float(acc2[2*k2]),
                                     __low2float (acc2[2*k2+1]),
                                     __high2float(acc2[2*k2+1]));
        *(float4*)&sO[(lr << 6) + ((ch ^ (lr & 15)) << 2)] = v;
    }
    __syncthreads();

    float4* op = (float4*)(out + (size_t)blockIdx.x * (128 * 64));
    #pragma unroll
    for (int j = 0; j < 8; ++j) {     // 2048 float4 = 32 KiB, contiguous
        const int F  = tid + (j << 8);
        const int r2 = F >> 4;
        const int m2 = F & 15;
        op[F] = *(const float4*)&sO[(r2 << 6) + ((m2 ^ (r2 & 15)) << 2)];
    }
}

extern "C" void kernel_launch(void* const* d_in, const int* in_sizes, int n_in,
                              void* d_out, int out_size, void* d_ws, size_t ws_size,
                              hipStream_t stream) {
    const float* I = (const float*)d_in[0];
    const float* A = (const float*)d_in[1];
    const float* T = (const float*)d_in[2];
    const float* L = (const float*)d_in[3];
    float* outp = (float*)d_out;

    const int nblocks = NROWS / 128;   // 1024 blocks x 256 threads
    halut_fwd<<<nblocks, 256, 0, stream>>>(I, A, T, L, outp);
}

// Round 14
// 29.390 us; speedup vs baseline: 2.3626x; 1.8173x over previous
//
#include <hip/hip_runtime.h>

// HalutMatmul forward on MI355X.
// Per row n: h[c][p] = sum_d I[n, c*9+d] * A[c][d][p]   (c=0..15, p=0..3)
//            code_c  = 4-level tree descent: bit_l = (h[c][l] > T[c*15 + node_l])
//            out[n][m] = sum_c L[m][c][code_c]
//
// Round-14: MFMA gather. R10 (27.4us, best) spent ~10us on the LDS gather +
// hadd2 + LDS-transpose epilogue. That whole tail IS a matmul:
//   out[n][m] = sum_k E[n][k] * B[k][m],  E = one-hot(codes), K=256,
//   B[k][m] = f16(L[m][c(k)][slot(k)]).
// A-frags (E) are built in REGISTERS from the codes (~12 VALU each, zero LDS);
// B-panel reads are 32 ds_read_b128/wave (vs 128/thread before); f32 accum;
// direct coalesced stores from the C/D layout (no epilogue LDS at all).
// Hash phase is R10 verbatim (f64 -> codes bit-exact).

#define NROWS (1024 * 128)

typedef _Float16 half8 __attribute__((ext_vector_type(8)));
typedef float    f32x4 __attribute__((ext_vector_type(4)));

__global__ __launch_bounds__(256, 2) void halut_fwd(
    const float* __restrict__ I,
    const float* __restrict__ A,
    const float* __restrict__ T,
    const float* __restrict__ L,
    float* __restrict__ out)
{
    __shared__ uint32_t sB[8192];          // 32 KB f16 B-panel, fragment layout
    __shared__ float    sStage[4][2304];   // wave-private I tiles (R10)
    __shared__ uint4    sCodesV[256];      // 256 rows x 16 codes (u8)

    uint8_t* sCodes = (uint8_t*)sCodesV;
    const int tid  = threadIdx.x;
    const int w    = tid >> 6;
    const int lane = tid & 63;
    const int cB   = lane & 15;            // hash: codebook
    const int g    = lane >> 4;            // hash: row-in-pass

    // ---- per-lane constants: codebook cB's A and T (f32; promoted inside the
    //      f64 FMA chain -> bit-identical codes to rounds 1-10) ----
    float Af[36];
    {
        const float4* ap4 = (const float4*)(A + cB * 36);   // 144B-aligned
        #pragma unroll
        for (int i = 0; i < 9; ++i) {
            const float4 v = ap4[i];
            Af[4*i+0] = v.x; Af[4*i+1] = v.y; Af[4*i+2] = v.z; Af[4*i+3] = v.w;
        }
    }
    float Tf[15];
    #pragma unroll
    for (int j = 0; j < 15; ++j) Tf[j] = T[cB * 15 + j];

    // ---- stage B-panel: B[k][m] = f16(L[m][c][slot]), fragment layout ----
    // j = c*2 + khalf (0..31); region r = (j>>2)*4 + ((j>>1)&1)*2 + (j&1);
    // chunk addr = r*1024 + m*16 (8 consecutive-k f16 for (m, k-group r%4)).
    // Lane l stages m = l, wave w stages j = w*8..w*8+7: ds_write is
    // base + l*16 -> contiguous 1KB, conflict-free.
    {
        const int m = lane;
        #pragma unroll
        for (int i = 0; i < 8; ++i) {
            const int j = w * 8 + i;
            const float4 f0 = *(const float4*)(L + (m * 32 + j) * 8);
            const float4 f1 = *(const float4*)(L + (m * 32 + j) * 8 + 4);
            union { uint32_t u[4]; half8 v; } pk;
            pk.v = (half8){(_Float16)f0.x, (_Float16)f0.y, (_Float16)f0.z, (_Float16)f0.w,
                           (_Float16)f1.x, (_Float16)f1.y, (_Float16)f1.z, (_Float16)f1.w};
            const int r = ((j >> 2) << 2) + (((j >> 1) & 1) << 1) + (j & 1);
            *(uint4*)((char*)sB + r * 1024 + m * 16) =
                make_uint4(pk.u[0], pk.u[1], pk.u[2], pk.u[3]);
        }
    }
    // no barrier yet: the post-hash barrier covers B-panel visibility.

    // ---- hash superphases (R10 verbatim): 4 x (stage 16 rows, 4 passes) ----
    const int wave_row0 = blockIdx.x * 256 + w * 64;
    const float4* Isrc = (const float4*)I;
    float4* st4 = (float4*)sStage[w];

    float4 nbuf[9];
    #pragma unroll
    for (int i = 0; i < 9; ++i)
        nbuf[i] = Isrc[(size_t)wave_row0 * 36 + i * 64 + lane];

    #pragma unroll
    for (int p16 = 0; p16 < 4; ++p16) {
        #pragma unroll
        for (int i = 0; i < 9; ++i) st4[i * 64 + lane] = nbuf[i];   // write-late
        if (p16 < 3) {                                               // issue-early
            #pragma unroll
            for (int i = 0; i < 9; ++i)
                nbuf[i] = Isrc[(size_t)(wave_row0 + (p16+1)*16) * 36 + i*64 + lane];
        }
        #pragma unroll
        for (int ps = 0; ps < 4; ++ps) {
            const int lr = ps * 4 + g;            // row 0..15 within chunk
            const float* xr = &sStage[w][lr * 144 + cB * 9];
            double h0 = 0.0, h1 = 0.0, h2 = 0.0, h3 = 0.0;
            #pragma unroll
            for (int d = 0; d < 9; ++d) {
                const double x = (double)xr[d];
                h0 = fma(x, (double)Af[4*d+0], h0);
                h1 = fma(x, (double)Af[4*d+1], h1);
                h2 = fma(x, (double)Af[4*d+2], h2);
                h3 = fma(x, (double)Af[4*d+3], h3);
            }
            uint32_t mk = 0;
            mk |= (h0 > (double)Tf[0])  ?     1u : 0u;   // node 0  (level 0)
            mk |= (h1 > (double)Tf[1])  ?     2u : 0u;   // node 1  (level 1)
            mk |= (h1 > (double)Tf[2])  ?     4u : 0u;   // node 2
            mk |= (h2 > (double)Tf[3])  ?     8u : 0u;   // node 3  (level 2)
            mk |= (h2 > (double)Tf[4])  ?    16u : 0u;   // node 4
            mk |= (h2 > (double)Tf[5])  ?    32u : 0u;   // node 5
            mk |= (h2 > (double)Tf[6])  ?    64u : 0u;   // node 6
            mk |= (h3 > (double)Tf[7])  ?   128u : 0u;   // node 7  (level 3)
            mk |= (h3 > (double)Tf[8])  ?   256u : 0u;   // node 8
            mk |= (h3 > (double)Tf[9])  ?   512u : 0u;   // node 9
            mk |= (h3 > (double)Tf[10]) ?  1024u : 0u;   // node 10
            mk |= (h3 > (double)Tf[11]) ?  2048u : 0u;   // node 11
            mk |= (h3 > (double)Tf[12]) ?  4096u : 0u;   // node 12
            mk |= (h3 > (double)Tf[13]) ?  8192u : 0u;   // node 13
            mk |= (h3 > (double)Tf[14]) ? 16384u : 0u;   // node 14
            int p =       (int)(mk & 1u);
            p = 2 * p + (int)((mk >> (1 + p)) & 1u);
            p = 2 * p + (int)((mk >> (3 + p)) & 1u);
            p = 2 * p + (int)((mk >> (7 + p)) & 1u);
            sCodes[(w * 64 + p16 * 16 + lr) * 16 + cB] = (uint8_t)p;
        }
    }
    __syncthreads();   // B-panel (cross-wave) + codes visible

    // ---- MFMA gather: wave w computes its 64 rows as 4 row-tiles of 16 ----
    const int lg = lane >> 4;         // k-group within fragment
    const int ln = lane & 15;         // A row / C col index

    uint4 cw[4];
    #pragma unroll
    for (int rt = 0; rt < 4; ++rt)    // lanes 16-63 broadcast-read rows 0-15
        cw[rt] = *(const uint4*)&sCodes[(w * 64 + rt * 16 + ln) * 16];

    f32x4 acc[4][4];
    #pragma unroll
    for (int rt = 0; rt < 4; ++rt)
        #pragma unroll
        for (int nb = 0; nb < 4; ++nb) acc[rt][nb] = (f32x4){0.f, 0.f, 0.f, 0.f};

    #pragma unroll
    for (int kt = 0; kt < 8; ++kt) {           // K-tile = 32 = 2 codebooks
        half8 bfr[4];
        #pragma unroll
        for (int nb = 0; nb < 4; ++nb) {       // B-frag: banks spread, 2-way max
            union { uint4 q; half8 v; } cv;
            cv.q = *(const uint4*)((const char*)sB + (kt*4 + lg) * 1024
                                                   + (nb*16 + ln) * 16);
            bfr[nb] = cv.v;
        }
        #pragma unroll
        for (int rt = 0; rt < 4; ++rt) {
            // code for (row = ln, c = 2kt + (lg>>1)); dword = kt>>1 (static)
            const uint32_t dw = (kt < 2) ? cw[rt].x : (kt < 4) ? cw[rt].y
                              : (kt < 6) ? cw[rt].z : cw[rt].w;
            const int      sh = (((2 * kt) & 3) << 3) + ((lg >> 1) << 3);
            const uint32_t code = (dw >> sh) & 0xffu;
            // one-hot A-frag: k_local = lg*8+e -> slot = (lg&1)*8+e
            const uint32_t off = code - ((uint32_t)(lg & 1) << 3);  // wraps if <
            const bool     inr = off < 8u;
            const uint32_t hw  = 0x3C00u << ((off & 1) << 4);       // f16 1.0
            union { uint32_t u[4]; half8 v; } af;
            #pragma unroll
            for (int i2 = 0; i2 < 4; ++i2)
                af.u[i2] = (inr && ((off >> 1) == (uint32_t)i2)) ? hw : 0u;
            #pragma unroll
            for (int nb = 0; nb < 4; ++nb)
                acc[rt][nb] = __builtin_amdgcn_mfma_f32_16x16x32_f16(
                                  af.v, bfr[nb], acc[rt][nb], 0, 0, 0);
        }
    }

    // ---- direct coalesced stores from C/D layout (row=(lg*4+j), col=ln) ----
    const size_t rowbase = (size_t)blockIdx.x * 256 + w * 64;
    #pragma unroll
    for (int rt = 0; rt < 4; ++rt)
        #pragma unroll
        for (int nb = 0; nb < 4; ++nb)
            #pragma unroll
            for (int j = 0; j < 4; ++j)
                out[(rowbase + rt*16 + lg*4 + j) * 64 + nb*16 + ln] = acc[rt][nb][j];
}

extern "C" void kernel_launch(void* const* d_in, const int* in_sizes, int n_in,
                              void* d_out, int out_size, void* d_ws, size_t ws_size,
                              hipStream_t stream) {
    const float* I = (const float*)d_in[0];
    const float* A = (const float*)d_in[1];
    const float* T = (const float*)d_in[2];
    const float* L = (const float*)d_in[3];
    float* outp = (float*)d_out;

    const int nblocks = NROWS / 256;   // 512 blocks x 256 threads, 256 rows/blk
    halut_fwd<<<nblocks, 256, 0, stream>>>(I, A, T, L, outp);
}